// Round 3
// baseline (66.113 us; speedup 1.0000x reference)
//
#include <hip/hip_runtime.h>
#include <cmath>

#define H 1024
#define V 50257
#define L 512
#define NB5 1571   // ceil(V/32) blocks for the out-GEMV

__device__ __forceinline__ float wred_sum(float v) {
#pragma unroll
    for (int o = 32; o > 0; o >>= 1) v += __shfl_xor(v, o, 64);
    return v;
}
__device__ __forceinline__ float dot4(float4 a, float4 b) {
    return a.x * b.x + a.y * b.y + a.z * b.z + a.w * b.w;
}
__device__ __forceinline__ void ms_merge(float& m, float& s, float m2, float s2) {
    float M = fmaxf(m, m2);
    if (M == -INFINITY) { m = M; s = 0.f; return; }
    s = s * expf(m - M) + s2 * expf(m2 - M);
    m = M;
}

// K1: horizontal fusion, grid 896:
//  blocks [0,128):  attn logits (4/block, wave-per-row) -> e^lg -> S atomic,
//                   e_lg stash, and immediate weighted-enc accumulate into
//                   4-way shadow-striped num[] via atomics (no softmax barrier).
//  blocks [128,896): gh[j] = h . W_hh[j,:] + b_hh[j]  (wave-per-row)
__global__ void k_phase1(const int* __restrict__ tok,
                         const float* __restrict__ hid,
                         const float* __restrict__ emb,
                         const float* __restrict__ Wa,
                         const float* __restrict__ ba,
                         const float* __restrict__ enc,
                         const float* __restrict__ Whh,
                         const float* __restrict__ bhh,
                         float* __restrict__ num4,   // [4][1024] zeroed
                         float* __restrict__ Sacc,   // [1] zeroed
                         float* __restrict__ elg,    // [512]
                         float* __restrict__ gh) {
    const int t = threadIdx.x;
    const int lane = t & 63, wv = t >> 6;
    const float4* h4 = (const float4*)hid;
    if (blockIdx.x < 128) {
        const int l = blockIdx.x * 4 + wv;
        const float4* e4 = (const float4*)(emb + (size_t)tok[0] * H);
        const float4* wr = (const float4*)(Wa + (size_t)l * 2048);
        float acc = 0.f;
#pragma unroll
        for (int k = 0; k < 8; ++k) {
            int f = 64 * k + lane;
            float4 s = (f < 256) ? e4[f] : h4[f - 256];
            acc += dot4(wr[f], s);
        }
        acc = wred_sum(acc);
        const float e = expf(acc + ba[l]);
        __shared__ float se[4];
        if (lane == 0) { se[wv] = e; elg[l] = e; }
        __syncthreads();
        if (t == 0) atomicAdd(Sacc, se[0] + se[1] + se[2] + se[3]);
        // weighted enc accumulate: thread t owns float4 column t
        float4 a = make_float4(0.f, 0.f, 0.f, 0.f);
#pragma unroll
        for (int r = 0; r < 4; ++r) {
            const float w = se[r];
            const float4 v = ((const float4*)(enc + (size_t)(blockIdx.x * 4 + r) * H))[t];
            a.x += w * v.x; a.y += w * v.y; a.z += w * v.z; a.w += w * v.w;
        }
        float* dst = num4 + (size_t)(blockIdx.x & 3) * 1024 + 4 * t;
        atomicAdd(dst + 0, a.x);
        atomicAdd(dst + 1, a.y);
        atomicAdd(dst + 2, a.z);
        atomicAdd(dst + 3, a.w);
    } else {
        const int j = (blockIdx.x - 128) * 4 + wv;   // [0, 3072)
        const float4* wh = (const float4*)(Whh + (size_t)j * H);
        float acc = 0.f;
#pragma unroll
        for (int k = 0; k < 4; ++k) {
            int f = 64 * k + lane;
            acc += dot4(wh[f], h4[f]);
        }
        acc = wred_sum(acc);
        if (lane == 0) gh[j] = acc + bhh[j];
    }
}

// K2: x[j] = relu([embedded, num/S] . W_comb[j,:] + b_comb[j]); wave-per-row.
//     Block 0 also writes attn_weights = e_lg / S to d_out.
__global__ void k_comb(const int* __restrict__ tok,
                       const float* __restrict__ emb,
                       const float* __restrict__ num4,
                       const float* __restrict__ Sacc,
                       const float* __restrict__ elg,
                       const float* __restrict__ Wc,
                       const float* __restrict__ bcb,
                       float* __restrict__ xv,
                       float* __restrict__ wout) {
    const int t = threadIdx.x;
    const int lane = t & 63, wv = t >> 6;
    const int j = blockIdx.x * 4 + wv;   // grid 256
    const float invS = 1.f / Sacc[0];
    const float4* e4 = (const float4*)(emb + (size_t)tok[0] * H);
    const float4* n4 = (const float4*)num4;
    const float4* wr = (const float4*)(Wc + (size_t)j * 2048);
    float acc = 0.f;
#pragma unroll
    for (int k = 0; k < 4; ++k) {
        int f = 64 * k + lane;
        acc += dot4(wr[f], e4[f]);
        float4 s0 = n4[f], s1 = n4[256 + f], s2 = n4[512 + f], s3 = n4[768 + f];
        float4 aa = make_float4((s0.x + s1.x + s2.x + s3.x) * invS,
                                (s0.y + s1.y + s2.y + s3.y) * invS,
                                (s0.z + s1.z + s2.z + s3.z) * invS,
                                (s0.w + s1.w + s2.w + s3.w) * invS);
        acc += dot4(wr[256 + f], aa);
    }
    acc = wred_sum(acc);
    if (lane == 0) xv[j] = fmaxf(acc + bcb[j], 0.f);
    if (blockIdx.x == 0) {
        wout[t] = elg[t] * invS;
        wout[t + 256] = elg[t + 256] * invS;
    }
}

// K3: fused gates+GRU; wave per j computes gi_r/gi_z/gi_n then the pointwise GRU.
__global__ void k_gates_gru(const float* __restrict__ xv,
                            const float* __restrict__ hid,
                            const float* __restrict__ Wih,
                            const float* __restrict__ bih,
                            const float* __restrict__ gh,
                            float* __restrict__ hn_out,
                            float* __restrict__ hn_ws) {
    const int lane = threadIdx.x & 63, wv = threadIdx.x >> 6;
    const int j = blockIdx.x * 4 + wv;   // grid 256
    const float4* x4 = (const float4*)xv;
    float4 xreg[4];
#pragma unroll
    for (int k = 0; k < 4; ++k) xreg[k] = x4[64 * k + lane];
    float g[3];
#pragma unroll
    for (int p = 0; p < 3; ++p) {
        const float4* wr = (const float4*)(Wih + (size_t)(j + p * H) * H);
        float acc = 0.f;
#pragma unroll
        for (int k = 0; k < 4; ++k) acc += dot4(wr[64 * k + lane], xreg[k]);
        g[p] = wred_sum(acc) + bih[j + p * H];
    }
    if (lane == 0) {
        float r = 1.f / (1.f + expf(-(g[0] + gh[j])));
        float z = 1.f / (1.f + expf(-(g[1] + gh[j + H])));
        float n = tanhf(g[2] + r * gh[j + 2 * H]);
        float hv = (1.f - z) * n + z * hid[j];
        hn_out[j] = hv;
        hn_ws[j] = hv;
    }
}

// K4: logits[v] = h_new . W_out[v,:] + b_out[v]; wave-per-row x 8 rows,
//     deferred wave-uniform (max,sumexp) partial per block.
__global__ void k_out_gemv(const float* __restrict__ hn,
                           const float* __restrict__ Wo,
                           const float* __restrict__ bo,
                           float* __restrict__ logits,
                           float* __restrict__ pm,
                           float* __restrict__ ps) {
    const int lane = threadIdx.x & 63, wv = threadIdx.x >> 6;
    const int b = blockIdx.x;
    const float4* h4 = (const float4*)hn;
    float4 hreg[4];
#pragma unroll
    for (int k = 0; k < 4; ++k) hreg[k] = h4[64 * k + lane];
    float lv[8];
    int nvalid = 0;
#pragma unroll
    for (int i = 0; i < 8; ++i) {
        const int v = b * 32 + wv * 8 + i;
        if (v < V) {
            const float4* wr = (const float4*)(Wo + (size_t)v * H);
            float acc = 0.f;
#pragma unroll
            for (int k = 0; k < 4; ++k) acc += dot4(wr[64 * k + lane], hreg[k]);
            acc = wred_sum(acc) + bo[v];
            if (lane == 0) logits[v] = acc;
            lv[nvalid++] = acc;   // wave-uniform
        }
    }
    float m = -INFINITY, s = 0.f;
    for (int i = 0; i < nvalid; ++i) m = fmaxf(m, lv[i]);
    for (int i = 0; i < nvalid; ++i) s += expf(lv[i] - m);
    __shared__ float smm[4], sms[4];
    if (lane == 0) { smm[wv] = m; sms[wv] = s; }
    __syncthreads();
    if (threadIdx.x == 0) {
        float M = smm[0], S = sms[0];
#pragma unroll
        for (int i = 1; i < 4; ++i) ms_merge(M, S, smm[i], sms[i]);
        pm[b] = M; ps[b] = S;
    }
}

// K5: redundant per-block reduce of 1571 (m,s) partials, then out[v] -= C.
__global__ void k_finalize(float* __restrict__ out,
                           const float* __restrict__ pm,
                           const float* __restrict__ ps) {
    const int t = threadIdx.x;
    const int lane = t & 63, wv = t >> 6;
    float m = -INFINITY, s = 0.f;
    for (int i = t; i < NB5; i += 256) ms_merge(m, s, pm[i], ps[i]);
#pragma unroll
    for (int o = 32; o > 0; o >>= 1) {
        float m2 = __shfl_xor(m, o, 64);
        float s2 = __shfl_xor(s, o, 64);
        ms_merge(m, s, m2, s2);
    }
    __shared__ float smm[4], sms[4];
    __shared__ float Cs;
    if (lane == 0) { smm[wv] = m; sms[wv] = s; }
    __syncthreads();
    if (t == 0) {
        float M = smm[0], S = sms[0];
#pragma unroll
        for (int i = 1; i < 4; ++i) ms_merge(M, S, smm[i], sms[i]);
        Cs = M + logf(S);
    }
    __syncthreads();
    const float C = Cs;
    const int v = blockIdx.x * 256 + t;
    if (v < V) out[v] -= C;
}

extern "C" void kernel_launch(void* const* d_in, const int* in_sizes, int n_in,
                              void* d_out, int out_size, void* d_ws, size_t ws_size,
                              hipStream_t stream) {
    const int*   tok = (const int*)d_in[0];
    const float* hid = (const float*)d_in[1];
    const float* enc = (const float*)d_in[2];
    const float* emb = (const float*)d_in[3];
    const float* Wa  = (const float*)d_in[4];
    const float* ba  = (const float*)d_in[5];
    const float* Wc  = (const float*)d_in[6];
    const float* bc  = (const float*)d_in[7];
    const float* Wih = (const float*)d_in[8];
    const float* Whh = (const float*)d_in[9];
    const float* bih = (const float*)d_in[10];
    const float* bhh = (const float*)d_in[11];
    const float* Wo  = (const float*)d_in[12];
    const float* bo  = (const float*)d_in[13];

    float* out = (float*)d_out;   // [V | H | L]
    float* ws  = (float*)d_ws;
    float* num4 = ws;             // 4096  shadow-striped attn numerator (zeroed)
    float* Sacc = ws + 4096;      // 1     exp-sum (zeroed)
    float* elg  = ws + 4112;      // 512   e^logit stash
    float* gh   = ws + 4624;      // 3072
    float* xv   = ws + 7696;      // 1024
    float* hn   = ws + 8720;      // 1024  (16B aligned)
    float* pm   = ws + 9744;      // 1571
    float* psum = ws + 11316;     // 1571

    float* out_logits = out;          // V
    float* out_hnew   = out + V;      // H
    float* out_attnw  = out + V + H;  // L

    hipMemsetAsync(ws, 0, 4097 * sizeof(float), stream);
    k_phase1<<<896, 256, 0, stream>>>(tok, hid, emb, Wa, ba, enc, Whh, bhh,
                                      num4, Sacc, elg, gh);
    k_comb<<<256, 256, 0, stream>>>(tok, emb, num4, Sacc, elg, Wc, bc, xv, out_attnw);
    k_gates_gru<<<256, 256, 0, stream>>>(xv, hid, Wih, bih, gh, out_hnew, hn);
    k_out_gemv<<<NB5, 256, 0, stream>>>(hn, Wo, bo, out_logits, pm, psum);
    k_finalize<<<197, 256, 0, stream>>>(out_logits, pm, psum);
}